// Round 12
// baseline (128.511 us; speedup 1.0000x reference)
//
#include <hip/hip_runtime.h>
#include <cmath>

#pragma clang fp contract(off)

#define NT 1024
constexpr int B_ = 256, Q_ = 300, C_ = 81, V_ = 117, K_ = 100;
constexpr int QC_ = Q_ * C_;   // 24300
constexpr int KV_ = K_ * V_;   // 11700
constexpr int CAP = 1024;      // LDS candidate buffer (fallback sort size)
constexpr int CMN = V_ * C_;   // 9477 floats = 37908 B

using u32 = unsigned int;
using u64 = unsigned long long;
using u16 = unsigned short;
using u8  = unsigned char;

// Histogram support: each softmax row max >= 1/81 -> T >= 482; values below
// 2^-7 (bin 480) can never participate. bits >= 0x3C000000 <=> bin >= 480
// exactly, so a 64-bin histogram over [480,544) gives a bit-identical T.
constexpr u32 PCUT_BITS = 0x3C000000u;
constexpr int BIN0 = 480;
constexpr int NB   = 64;
// 8-way sub-banked histogram (r10): spreads hot-bin atomics over 8 slots.
constexpr int HREP = 8;

// ---- LDS layout (lifetime-aliased, hand-packed; 54,848 B) ----
constexpr int OFF_CM   = 0;                 // f32[9477] = 37908 B, staged during phase 5
constexpr int OFF_HIST = 37920;             // u32[64*8]=2048 | cand u64[1024]=8192 | areas
constexpr int OFF_RMAX = OFF_HIST + 8192;   // f32[309] PADDED: idx r+(r>>5)
constexpr int OFF_RINV = OFF_RMAX + 1240;   // f32[309] padded likewise
constexpr int OFF_BSUB = OFF_RINV + 1240;   // f32[100][4] (16B aligned)
constexpr int OFF_BOBJ = OFF_BSUB + 1600;   // f32[100][4] | wred u64[16] (fallback 5c)
constexpr int OFF_SUPR = OFF_BOBJ + 1600;   // u32[100][4] col-major supmat | s_prev u64 (5c)
constexpr int OFF_SELV = OFF_SUPR + 1600;   // f32[100]
constexpr int OFF_SELI = OFF_SELV + 400;    // u32[100] flat topk index
constexpr int OFF_MAXB = OFF_SELI + 400;    // u32[100] row-max bits
constexpr int OFF_ORD  = OFF_MAXB + 400;    // u8[100] (pad 104)
constexpr int OFF_LAB  = OFF_ORD + 104;     // u8[100] labels (pad 104)
constexpr int OFF_MISC = OFF_LAB + 104;     // skeep[4], keep_bits[4], s_cnt, sT
constexpr int SMEM_SZ  = OFF_MISC + 48;     // 54,848
static_assert(SMEM_SZ <= 65536, "LDS overflow");
static_assert((OFF_BSUB & 15) == 0 && (OFF_BOBJ & 15) == 0, "b128 align");
static_assert(OFF_HIST >= OFF_CM + CMN * 4, "cm/hist overlap");
static_assert((OFF_HIST & 15) == 0, "cand/hist align");

// Raw LDS-only barrier (r9): waits only lgkmcnt so global stores keep
// draining underneath subsequent phases. The one cross-wave global-order
// need (phase-6 o0 stores before phase-9 zeroing) is the full
// __syncthreads() before phase 9.
__device__ __forceinline__ void bar_lds() {
    asm volatile("s_waitcnt lgkmcnt(0)\n\ts_barrier" ::: "memory");
}

// padded row-stat index: r + r/32 (fixes the 32-way bank conflict of r5).
__device__ __forceinline__ int RM(int r) { return r + (r >> 5); }

__device__ __forceinline__ u64 shfl_xor_u64(u64 v, int mask) {
    u32 lo = (u32)v, hi = (u32)(v >> 32);
    lo = (u32)__shfl_xor((int)lo, mask, 64);
    hi = (u32)__shfl_xor((int)hi, mask, 64);
    return ((u64)hi << 32) | lo;
}

// ---- exact butterfly-exchange primitives (same lane pairing as __shfl_xor) --
template <int CTRL>
__device__ __forceinline__ int dpp_i(int x) {
    return __builtin_amdgcn_update_dpp(0, x, CTRL, 0xF, 0xF, true);
}
__device__ __forceinline__ float bfly16(float x){ return __int_as_float(__builtin_amdgcn_ds_swizzle(__float_as_int(x), 0x401F)); }
__device__ __forceinline__ float bfly8 (float x){ return __int_as_float(dpp_i<0x128>(__float_as_int(x))); }
__device__ __forceinline__ float bfly4 (float x){ return __int_as_float(__builtin_amdgcn_ds_swizzle(__float_as_int(x), 0x101F)); }
__device__ __forceinline__ float bfly2 (float x){ return __int_as_float(dpp_i<0x4E>(__float_as_int(x))); }
__device__ __forceinline__ float bfly1 (float x){ return __int_as_float(dpp_i<0xB1>(__float_as_int(x))); }
__device__ __forceinline__ int ibfly4(int x){ return __builtin_amdgcn_ds_swizzle(x, 0x101F); }
__device__ __forceinline__ int ibfly2(int x){ return dpp_i<0x4E>(x); }
__device__ __forceinline__ int ibfly1(int x){ return dpp_i<0xB1>(x); }

// bit-identical to original: inter / ((areaA + areaB) - inter)
__device__ __forceinline__ float iou4(float4 a, float4 b, float areaSum) {
    float xx1 = fmaxf(a.x, b.x);
    float yy1 = fmaxf(a.y, b.y);
    float xx2 = fminf(a.z, b.z);
    float yy2 = fminf(a.w, b.w);
    float w = fmaxf(0.f, xx2 - xx1 + 1.f);
    float h = fmaxf(0.f, yy2 - yy1 + 1.f);
    float inter = w * h;
    return inter / (areaSum - inter);
}

__global__ __launch_bounds__(NT, 4) void hoi_kernel(
    const float* __restrict__ obj_logits,   // B,Q,C
    const float* __restrict__ verb_logits,  // B,Q,V
    const float* __restrict__ sub_boxes_in, // B,Q,4
    const float* __restrict__ obj_boxes_in, // B,Q,4
    const float* __restrict__ cm,           // V,C
    const int*   __restrict__ tsizes,       // B,2 (h,w)
    float* __restrict__ out)
{
    const int b = blockIdx.x;
    const int tid = threadIdx.x;

    __shared__ __align__(16) u8 smem[SMEM_SZ];
    float* cml     = (float*)(smem + OFF_CM);
    u32*   hist    = (u32*)(smem + OFF_HIST);
    u64*   cand    = (u64*)(smem + OFF_HIST);
    float* asub    = (float*)(smem + OFF_HIST);        // phase>=5.5 (hist/cand dead)
    float* aobj    = (float*)(smem + OFF_HIST + 512);  // phase>=5.5
    float* rowmax  = (float*)(smem + OFF_RMAX);
    float* rinv    = (float*)(smem + OFF_RINV);
    float (*bsub)[4]   = (float(*)[4])(smem + OFF_BSUB);
    float (*bobj)[4]   = (float(*)[4])(smem + OFF_BOBJ);
    u32   (*supcol)[4] = (u32(*)[4])(smem + OFF_SUPR); // column-major suppression bits
    float* sel_val = (float*)(smem + OFF_SELV);
    u32*   sel_idx = (u32*)(smem + OFF_SELI);
    u32*   maxbits = (u32*)(smem + OFF_MAXB);
    u8*    order8  = (u8*)(smem + OFF_ORD);
    u8*    lab8    = (u8*)(smem + OFF_LAB);
    u32*   skeep     = (u32*)(smem + OFF_MISC);
    u32*   keep_bits = (u32*)(smem + OFF_MISC + 16);
    u32*   s_cnt     = (u32*)(smem + OFF_MISC + 32);
    int*   sT        = (int*)(smem + OFF_MISC + 36);
    u64*   wred    = (u64*)(smem + OFF_BOBJ);   // 5c scratch
    u64*   s_prev  = (u64*)(smem + OFF_SUPR);   // 5c scratch

    const float* lg = obj_logits + (size_t)b * QC_;

    // ---- Output pointers (concatenated in return order) ----
    float* o0 = out;                                   // final_scores B,K,V
    float* o1 = out + (size_t)B_ * KV_;                // topk_values  B,K
    float* o2 = o1 + (size_t)B_ * K_;                  // obj_labels   B,K
    float* o3 = o2 + (size_t)B_ * K_;                  // sub_boxes    B,K,4
    float* o4 = o3 + (size_t)B_ * K_ * 4;              // obj_boxes    B,K,4
    float* o5 = o4 + (size_t)B_ * K_ * 4;              // keep         B,K

    // ---- Phase 0: zero sub-banked hist + s_cnt (LDS only) ----
    if (tid < NB * HREP) hist[tid] = 0;
    if (tid == 0) *s_cnt = 0;
    bar_lds();

    // ---- Phase 1 (fused): softmax + histogram. All 30 loads issued up
    // front (full load ILP), but COMPUTE runs in two 5-row halves so peak
    // register liveness (~50) stays within what the allocator will grant —
    // the 10-wide version's ~70 live values made it re-serialize the loads
    // (VGPR_Count stuck at 36, exposed HBM latency per small batch).
    // Per-row arithmetic + reduce pairing identical -> bit-identical.
    const int g = tid >> 5, l = tid & 31;
    const bool have2 = (l < C_ - 64);   // l < 17
    const int hsub = tid & (HREP - 1);
    u32 cmask = 0;
    {
        float A0[5], A1[5], A2[5], B0[5], B1[5], B2[5];
        #pragma unroll
        for (int s = 0; s < 5; ++s) {
            int r = g + 32 * s;
            const float* row = lg + (size_t)((r < Q_ ? r : Q_ - 1) * C_);
            A0[s] = row[l];
            A1[s] = row[l + 32];
            A2[s] = have2 ? row[l + 64] : -INFINITY;
        }
        #pragma unroll
        for (int s = 0; s < 5; ++s) {
            int r = g + 32 * (s + 5);
            const float* row = lg + (size_t)((r < Q_ ? r : Q_ - 1) * C_);
            B0[s] = row[l];
            B1[s] = row[l + 32];
            B2[s] = have2 ? row[l + 64] : -INFINITY;
        }

        auto half5 = [&](float* v0, float* v1, float* v2, int sb) {
            float m[5];
            #pragma unroll
            for (int s = 0; s < 5; ++s) m[s] = fmaxf(fmaxf(v0[s], v1[s]), v2[s]);
            #pragma unroll
            for (int s = 0; s < 5; ++s) m[s] = fmaxf(m[s], bfly16(m[s]));
            #pragma unroll
            for (int s = 0; s < 5; ++s) m[s] = fmaxf(m[s], bfly8(m[s]));
            #pragma unroll
            for (int s = 0; s < 5; ++s) m[s] = fmaxf(m[s], bfly4(m[s]));
            #pragma unroll
            for (int s = 0; s < 5; ++s) m[s] = fmaxf(m[s], bfly2(m[s]));
            #pragma unroll
            for (int s = 0; s < 5; ++s) m[s] = fmaxf(m[s], bfly1(m[s]));
            float e0[5], e1[5], e2[5], sm[5];
            #pragma unroll
            for (int s = 0; s < 5; ++s) {
                e0[s] = expf(v0[s] - m[s]);
                e1[s] = expf(v1[s] - m[s]);
                e2[s] = have2 ? expf(v2[s] - m[s]) : 0.f;
                sm[s] = e0[s] + e1[s] + e2[s];
            }
            #pragma unroll
            for (int s = 0; s < 5; ++s) sm[s] += bfly16(sm[s]);
            #pragma unroll
            for (int s = 0; s < 5; ++s) sm[s] += bfly8(sm[s]);
            #pragma unroll
            for (int s = 0; s < 5; ++s) sm[s] += bfly4(sm[s]);
            #pragma unroll
            for (int s = 0; s < 5; ++s) sm[s] += bfly2(sm[s]);
            #pragma unroll
            for (int s = 0; s < 5; ++s) sm[s] += bfly1(sm[s]);
            #pragma unroll
            for (int s = 0; s < 5; ++s) {
                int sg = sb + s;
                int r = g + 32 * sg;
                if (r < Q_) {
                    float ri = 1.f / sm[s];
                    float p0 = e0[s] * ri, p1 = e1[s] * ri;
                    u32 x0 = __float_as_uint(p0), x1 = __float_as_uint(p1);
                    if (x0 >= PCUT_BITS) {
                        atomicAdd(&hist[(((x0 >> 21) - BIN0) << 3) + hsub], 1u);
                        cmask |= 1u << (3 * sg);
                    }
                    if (x1 >= PCUT_BITS) {
                        atomicAdd(&hist[(((x1 >> 21) - BIN0) << 3) + hsub], 1u);
                        cmask |= 1u << (3 * sg + 1);
                    }
                    if (have2) {
                        float p2 = e2[s] * ri;
                        u32 x2 = __float_as_uint(p2);
                        if (x2 >= PCUT_BITS) {
                            atomicAdd(&hist[(((x2 >> 21) - BIN0) << 3) + hsub], 1u);
                            cmask |= 1u << (3 * sg + 2);
                        }
                    }
                    if (l == 0) { rowmax[RM(r)] = m[s]; rinv[RM(r)] = ri; }
                }
            }
        };
        half5(A0, A1, A2, 0);   // B's 15 loads keep draining underneath
        half5(B0, B1, B2, 5);
    }
    bar_lds();

    // ---- Phase 3: threshold bin T — sum 8 sub-counters, 64-bin suffix scan ----
    if (tid < 64) {
        uint4 ha = ((const uint4*)hist)[tid * 2];
        uint4 hb = ((const uint4*)hist)[tid * 2 + 1];
        u32 suf = ha.x + ha.y + ha.z + ha.w + hb.x + hb.y + hb.z + hb.w;
        #pragma unroll
        for (int off = 1; off < 64; off <<= 1) {
            u32 o = (u32)__shfl_down((int)suf, off, 64);
            suf += (tid + off < 64) ? o : 0;
        }
        u32 nxt = (u32)__shfl_down((int)suf, 1, 64);
        if (tid == 63) nxt = 0;
        if (suf >= (u32)K_ && nxt < (u32)K_) *sT = BIN0 + tid;
    }
    bar_lds();   // T visible; hist dead (cand may alias)
    const int T = *sT;

    // ---- Phase 4: candidate scan driven by the mask — recompute prob,
    // bit-identical to phase 1 (same expf(v-m)*ri, same m/ri from LDS). ----
    u32 mk = cmask;
    while (mk) {
        int bpos = (int)__builtin_ctz(mk);
        mk &= mk - 1;
        int s = (bpos * 171) >> 9;       // floor(bpos/3) for bpos in [0,30)
        int c = bpos - 3 * s;
        int r = g + 32 * s;
        int col = l + 32 * c;
        int i = r * C_ + col;
        float p = expf(lg[i] - rowmax[RM(r)]) * rinv[RM(r)];
        u32 xb = __float_as_uint(p);
        if ((int)(xb >> 21) >= T) {
            u32 pos = atomicAdd(s_cnt, 1u);
            if (pos < (u32)CAP)
                cand[pos] = ((u64)xb << 32) | (u32)(~i);
        }
    }
    bar_lds();
    const int ncand = (int)*s_cnt;

    // ---- cm staging: issue 3 float4 loads/thread; rank scan runs under
    // their latency; ds_writes + bar_lds publish cml before phase 6. ----
    constexpr int CM4 = CMN / 4;              // 2369
    const float4* cmg4 = (const float4*)cm;
    float4 cc0 = cmg4[tid];
    float4 cc1 = cmg4[tid + NT];
    float4 cc2 = (tid < CM4 - 2 * NT) ? cmg4[tid + 2 * NT]
                                      : make_float4(0.f, 0.f, 0.f, 0.f);
    float ctail = (tid == 0) ? cm[CMN - 1] : 0.f;   // 9477 = 2369*4 + 1

    if (ncand <= CAP) {
        // ---- Phase 5: parallel rank-by-count top-K select (broadcast reads) ----
        if (tid < ncand) {
            u64 mykey = cand[tid];
            int rank = 0;
            int f = 0;
            for (; f + 4 <= ncand; f += 4) {
                u64 k0 = cand[f], k1 = cand[f + 1];
                u64 k2 = cand[f + 2], k3 = cand[f + 3];
                rank += (k0 > mykey) ? 1 : 0;
                rank += (k1 > mykey) ? 1 : 0;
                rank += (k2 > mykey) ? 1 : 0;
                rank += (k3 > mykey) ? 1 : 0;
            }
            for (; f < ncand; ++f) rank += (cand[f] > mykey) ? 1 : 0;
            if (rank < K_) {
                sel_val[rank] = __uint_as_float((u32)(mykey >> 32));
                sel_idx[rank] = ~(u32)mykey;
            }
        }
    } else {
        // ---- Phase 5c (near-dead): 100-round argmax with strict-less chaining ----
        if (tid == 0) *s_prev = ~0ull;
        __syncthreads();
        for (int r = 0; r < K_; r++) {
            u64 prev = *s_prev;
            u64 local = 0;
            for (int i = tid; i < QC_; i += NT) {
                int q = i / C_;
                float p = expf(lg[i] - rowmax[RM(q)]) * rinv[RM(q)];
                u64 key = ((u64)__float_as_uint(p) << 32) | (u32)(~i);
                if (key < prev && key > local) local = key;
            }
            for (int off = 32; off > 0; off >>= 1) {
                u64 o = shfl_xor_u64(local, off);
                if (o > local) local = o;
            }
            if ((tid & 63) == 0) wred[tid >> 6] = local;
            __syncthreads();
            if (tid == 0) {
                u64 m = wred[0];
                for (int wv = 1; wv < 16; wv++) if (wred[wv] > m) m = wred[wv];
                *s_prev = m;
                u32 idx = ~(u32)m;
                if (idx >= (u32)QC_) idx = 0;
                sel_val[r] = __uint_as_float((u32)(m >> 32));
                sel_idx[r] = idx;
            }
            __syncthreads();
        }
    }

    // publish cm to LDS (loads have had the whole rank scan to complete)
    ((float4*)cml)[tid] = cc0;
    ((float4*)cml)[tid + NT] = cc1;
    if (tid < CM4 - 2 * NT) ((float4*)cml)[tid + 2 * NT] = cc2;
    if (tid == 0) cml[CMN - 1] = ctail;
    bar_lds();   // sel_* AND cml visible; hist/cand/rowstats dead

    // ---- Fused phase 5.5+6+6.5 (full-wave per-row, r11). ----
    const int w = tid >> 6, lane = tid & 63;
    const int off0 = lane * C_;             // cml col offsets, lane-invariant
    const int off1 = (lane + 64) * C_;
    const bool l53 = (lane < V_ - 64);      // lane < 53

    const bool doSub = (tid < K_);
    const bool doObj = (tid >= 512 && tid < 512 + K_);
    float4 boxv = make_float4(0.f, 0.f, 0.f, 0.f);
    float biw = 0.f, bih = 0.f;
    if (doSub || doObj) {
        int t = doSub ? tid : tid - 512;
        int idx = (int)sel_idx[t];
        int q = idx / C_;
        biw = (float)tsizes[b * 2 + 1];
        bih = (float)tsizes[b * 2 + 0];
        boxv = doSub ? ((const float4*)sub_boxes_in)[(size_t)b * Q_ + q]
                     : ((const float4*)obj_boxes_in)[(size_t)b * Q_ + q];
    }
    if (tid >= 200 && tid < 200 + K_) {
        int t = tid - 200;
        supcol[t][0] = 0; supcol[t][1] = 0; supcol[t][2] = 0; supcol[t][3] = 0;
    } else if (tid >= 320 && tid < 324) {
        keep_bits[tid - 320] = 0;
    }

    {
        const float* vbase = verb_logits + (size_t)b * Q_ * V_;
        float* obase = o0 + (size_t)b * KV_;
        int c = w;                                   // w < 16 <= 100: >=1 row/wave
        u32 idx = sel_idx[c];
        int q = (int)idx / C_, lab = (int)idx - q * C_;
        float sv = sel_val[c];
        const float* vr = vbase + (size_t)q * V_;
        float x0 = vr[lane];
        float x1 = l53 ? vr[lane + 64] : 0.f;
        while (true) {
            int cn = c + 16;                         // wave-uniform
            int labn = 0; float svn = 0.f, x0n = 0.f, x1n = 0.f;
            if (cn < K_) {                           // prefetch next row
                u32 idxn = sel_idx[cn];
                int qn = (int)idxn / C_;
                labn = (int)idxn - qn * C_;
                svn = sel_val[cn];
                const float* vrn = vbase + (size_t)qn * V_;
                x0n = vrn[lane];
                x1n = l53 ? vrn[lane + 64] : 0.f;
            }
            // compute current row (expression order identical to before)
            float cv0 = cml[off0 + lab];
            float cv1 = l53 ? cml[off1 + lab] : 0.f;
            float h0 = (1.f / (1.f + expf(-x0))) * sv * cv0;
            float h1 = l53 ? (1.f / (1.f + expf(-x1))) * sv * cv1 : 0.f;
            float* orow = obase + c * V_;
            orow[lane] = h0;
            if (l53) orow[lane + 64] = h1;
            float m = fmaxf(h0, h1);                 // h >= 0; fmax exact
            m = fmaxf(m, __shfl_xor(m, 32, 64));
            m = fmaxf(m, bfly16(m));
            m = fmaxf(m, bfly8(m));
            m = fmaxf(m, bfly4(m));
            m = fmaxf(m, bfly2(m));
            m = fmaxf(m, bfly1(m));
            if (lane == 0) { maxbits[c] = __float_as_uint(m); lab8[c] = (u8)lab; }
            if (cn >= K_) break;
            c = cn; lab = labn; sv = svn; x0 = x0n; x1 = x1n;
        }
    }

    // finish boxes (loads issued before the row loop)
    if (doSub) {
        int t = tid;
        float x1v = (boxv.x - 0.5f * boxv.z) * biw, y1v = (boxv.y - 0.5f * boxv.w) * bih;
        float x2v = (boxv.x + 0.5f * boxv.z) * biw, y2v = (boxv.y + 0.5f * boxv.w) * bih;
        bsub[t][0] = x1v; bsub[t][1] = y1v; bsub[t][2] = x2v; bsub[t][3] = y2v;
        asub[t] = (x2v - x1v + 1.f) * (y2v - y1v + 1.f);
    } else if (doObj) {
        int t = tid - 512;
        float x1v = (boxv.x - 0.5f * boxv.z) * biw, y1v = (boxv.y - 0.5f * boxv.w) * bih;
        float x2v = (boxv.x + 0.5f * boxv.z) * biw, y2v = (boxv.y + 0.5f * boxv.w) * bih;
        bobj[t][0] = x1v; bobj[t][1] = y1v; bobj[t][2] = x2v; bobj[t][3] = y2v;
        aobj[t] = (x2v - x1v + 1.f) * (y2v - y1v + 1.f);
    }
    bar_lds();   // LDS (maxbits/lab8/boxes/areas/supcol/keep_bits) visible;
                 // o0 global stores keep draining underneath phases 7/8

    // ---- Phase 7: stable descending rank, 8 lanes/row, exact int sums ----
    if (tid < 800) {
        int r = tid >> 3, j = tid & 7;
        u64 kr = ((u64)maxbits[r] << 32) | (u32)(~r);
        int rank = 0;
        for (int k = 0; k < 13; k++) {
            int jj = j * 13 + k;
            if (jj < K_) {
                u64 kj = ((u64)maxbits[jj] << 32) | (u32)(~jj);
                rank += (kj > kr) ? 1 : 0;
            }
        }
        rank += ibfly4(rank);
        rank += ibfly2(rank);
        rank += ibfly1(rank);
        if (j == 0) order8[rank] = (u8)r;
    }
    bar_lds();

    // ---- Early output writes: o1..o4 depend only on sel/boxes (NOT keep) ----
    if (tid < K_) {
        o1[(size_t)b * K_ + tid] = sel_val[tid];
        o2[(size_t)b * K_ + tid] = (float)(sel_idx[tid] % (u32)C_);
    }
    if (tid >= 128 && tid < 128 + K_ * 4) {
        int t = tid - 128;
        int r = t >> 2, k = t & 3;
        o3[((size_t)b * K_) * 4 + t] = bsub[r][k];
        o4[((size_t)b * K_) * 4 + t] = bobj[r][k];
    }

    // ---- Phase 8a: 100x100 suppression bitmatrix, COLUMN-major
    // (division-free index stepping: e += NT <=> i += 10, j += 24) ----
    {
        int i = tid / K_, j = tid - (tid / K_) * K_;
        for (int e = tid; e < K_ * K_; e += NT) {
            if (j > i) {
                int ri = order8[i], rj = order8[j];
                u32 li = lab8[ri], lj = lab8[rj];
                if (li == lj) {
                    float4 s_i = *(const float4*)bsub[ri];
                    float4 s_j = *(const float4*)bsub[rj];
                    float4 b_i = *(const float4*)bobj[ri];
                    float4 b_j = *(const float4*)bobj[rj];
                    float o = iou4(s_i, s_j, asub[ri] + asub[rj]) *
                              iou4(b_i, b_j, aobj[ri] + aobj[rj]);
                    if (o > 0.5f)
                        atomicOr(&supcol[j][i >> 5], 1u << (i & 31));
                }
            }
            i += 10; j += 24;                  // NT = 10*K_ + 24
            if (j >= K_) { j -= K_; i += 1; }
        }
    }
    bar_lds();

    // ---- Phase 8b: greedy scan via ballot ----
    if (tid < 64) {
        u32 cA[4], cB[4];
        #pragma unroll
        for (int ww = 0; ww < 4; ++ww) cA[ww] = supcol[tid][ww];
        #pragma unroll
        for (int ww = 0; ww < 4; ++ww) cB[ww] = (tid < K_ - 64) ? supcol[tid + 64][ww] : 0u;
        bool sA = false, sB = false;
        u32 km[4] = {0, 0, 0, 0};
        #pragma unroll
        for (int i = 0; i < 64; ++i) {
            u64 bal = __ballot(sA);
            if (!((bal >> i) & 1)) {          // uniform branch
                km[i >> 5] |= 1u << (i & 31);
                sA = sA || ((cA[i >> 5] >> (i & 31)) & 1u);
                sB = sB || ((cB[i >> 5] >> (i & 31)) & 1u);
            }
        }
        #pragma unroll
        for (int i = 64; i < K_; ++i) {
            u64 bal = __ballot(sB);
            if (!((bal >> (i - 64)) & 1)) {   // uniform branch
                km[i >> 5] |= 1u << (i & 31);
                sA = sA || ((cA[i >> 5] >> (i & 31)) & 1u);
                sB = sB || ((cB[i >> 5] >> (i & 31)) & 1u);
            }
        }
        if (tid == 0) { skeep[0] = km[0]; skeep[1] = km[1]; skeep[2] = km[2]; skeep[3] = km[3]; }
    }
    bar_lds();
    if (tid < K_) {
        if ((skeep[tid >> 5] >> (tid & 31)) & 1u) {
            int r = order8[tid];
            atomicOr(&keep_bits[r >> 5], 1u << (r & 31));
        }
    }
    // FULL barrier (vmcnt drain): guarantees every wave's phase-6 o0 stores
    // are complete before phase 9's zeroing stores to the same addresses.
    __syncthreads();

    // ---- Phase 9: zero suppressed rows of o0 (per-wave coalesced), o5 keep ----
    for (int c = w; c < K_; c += 16) {
        if (!((keep_bits[c >> 5] >> (c & 31)) & 1u)) {
            float* orow = o0 + (size_t)b * KV_ + c * V_;
            orow[lane] = 0.f;
            if (l53) orow[lane + 64] = 0.f;
        }
    }
    if (tid < K_) {
        bool kp = (keep_bits[tid >> 5] >> (tid & 31)) & 1u;
        o5[(size_t)b * K_ + tid] = kp ? 1.f : 0.f;
    }
}

extern "C" void kernel_launch(void* const* d_in, const int* in_sizes, int n_in,
                              void* d_out, int out_size, void* d_ws, size_t ws_size,
                              hipStream_t stream) {
    const float* obj_logits  = (const float*)d_in[0];
    const float* verb_logits = (const float*)d_in[1];
    const float* sub_boxes   = (const float*)d_in[2];
    const float* obj_boxes   = (const float*)d_in[3];
    const float* cm          = (const float*)d_in[4];
    const int*   ts          = (const int*)d_in[5];
    hipLaunchKernelGGL(hoi_kernel, dim3(B_), dim3(NT), 0, stream,
                       obj_logits, verb_logits, sub_boxes, obj_boxes, cm, ts,
                       (float*)d_out);
}

// Round 13
// 127.687 us; speedup vs baseline: 1.0065x; 1.0065x over previous
//
#include <hip/hip_runtime.h>
#include <cmath>

#pragma clang fp contract(off)

#define NT 1024
constexpr int B_ = 256, Q_ = 300, C_ = 81, V_ = 117, K_ = 100;
constexpr int QC_ = Q_ * C_;   // 24300
constexpr int KV_ = K_ * V_;   // 11700
constexpr int CAP = 1024;      // LDS candidate buffer (fallback sort size)
constexpr int CMN = V_ * C_;   // 9477 floats = 37908 B
constexpr int NSTG = 96;       // rows staged to LDS via global_load_lds
constexpr int NF4  = NSTG * C_ / 4;   // 1944 float4s = 31104 B

using u32 = unsigned int;
using u64 = unsigned long long;
using u16 = unsigned short;
using u8  = unsigned char;

// Histogram support: each softmax row max >= 1/81 -> T >= 482; values below
// 2^-7 (bin 480) can never participate. bits >= 0x3C000000 <=> bin >= 480
// exactly, so a 64-bin histogram over [480,544) gives a bit-identical T.
constexpr u32 PCUT_BITS = 0x3C000000u;
constexpr int BIN0 = 480;
constexpr int NB   = 64;
// 8-way sub-banked histogram (r10): spreads hot-bin atomics over 8 slots.
constexpr int HREP = 8;

// ---- LDS layout (lifetime-aliased, hand-packed; 54,848 B) ----
// [0, 31104): staged logits rows 0..95 (phase 0-4) | cm f32[9477] (phase>=5)
constexpr int OFF_CM   = 0;
constexpr int OFF_HIST = 37920;             // u32[64*8]=2048 | cand u64[1024]=8192 | areas
constexpr int OFF_RMAX = OFF_HIST + 8192;   // f32[309] PADDED: idx r+(r>>5)
constexpr int OFF_RINV = OFF_RMAX + 1240;   // f32[309] padded likewise
constexpr int OFF_BSUB = OFF_RINV + 1240;   // f32[100][4] (16B aligned)
constexpr int OFF_BOBJ = OFF_BSUB + 1600;   // f32[100][4] | wred u64[16] (fallback 5c)
constexpr int OFF_SUPR = OFF_BOBJ + 1600;   // u32[100][4] col-major supmat | s_prev u64 (5c)
constexpr int OFF_SELV = OFF_SUPR + 1600;   // f32[100]
constexpr int OFF_SELI = OFF_SELV + 400;    // u32[100] flat topk index
constexpr int OFF_MAXB = OFF_SELI + 400;    // u32[100] row-max bits
constexpr int OFF_ORD  = OFF_MAXB + 400;    // u8[100] (pad 104)
constexpr int OFF_LAB  = OFF_ORD + 104;     // u8[100] labels (pad 104)
constexpr int OFF_MISC = OFF_LAB + 104;     // skeep[4], keep_bits[4], s_cnt, sT
constexpr int SMEM_SZ  = OFF_MISC + 48;     // 54,848
static_assert(SMEM_SZ <= 65536, "LDS overflow");
static_assert((OFF_BSUB & 15) == 0 && (OFF_BOBJ & 15) == 0, "b128 align");
static_assert(OFF_HIST >= NSTG * C_ * 4, "staged-logits/hist overlap");
static_assert(OFF_HIST >= OFF_CM + CMN * 4 - 4096 || true, "cm aliases staged region after phase 4");
static_assert((OFF_HIST & 15) == 0, "cand/hist align");

// Raw LDS-only barrier (r9): waits only lgkmcnt so global stores keep
// draining underneath subsequent phases. The one cross-wave global-order
// need (phase-6 o0 stores before phase-9 zeroing) is the full
// __syncthreads() before phase 9.
__device__ __forceinline__ void bar_lds() {
    asm volatile("s_waitcnt lgkmcnt(0)\n\ts_barrier" ::: "memory");
}

// padded row-stat index: r + r/32 (fixes the 32-way bank conflict of r5).
__device__ __forceinline__ int RM(int r) { return r + (r >> 5); }

__device__ __forceinline__ u64 shfl_xor_u64(u64 v, int mask) {
    u32 lo = (u32)v, hi = (u32)(v >> 32);
    lo = (u32)__shfl_xor((int)lo, mask, 64);
    hi = (u32)__shfl_xor((int)hi, mask, 64);
    return ((u64)hi << 32) | lo;
}

// ---- exact butterfly-exchange primitives (same lane pairing as __shfl_xor) --
template <int CTRL>
__device__ __forceinline__ int dpp_i(int x) {
    return __builtin_amdgcn_update_dpp(0, x, CTRL, 0xF, 0xF, true);
}
__device__ __forceinline__ float bfly16(float x){ return __int_as_float(__builtin_amdgcn_ds_swizzle(__float_as_int(x), 0x401F)); }
__device__ __forceinline__ float bfly8 (float x){ return __int_as_float(dpp_i<0x128>(__float_as_int(x))); }
__device__ __forceinline__ float bfly4 (float x){ return __int_as_float(__builtin_amdgcn_ds_swizzle(__float_as_int(x), 0x101F)); }
__device__ __forceinline__ float bfly2 (float x){ return __int_as_float(dpp_i<0x4E>(__float_as_int(x))); }
__device__ __forceinline__ float bfly1 (float x){ return __int_as_float(dpp_i<0xB1>(__float_as_int(x))); }
__device__ __forceinline__ int ibfly4(int x){ return __builtin_amdgcn_ds_swizzle(x, 0x101F); }
__device__ __forceinline__ int ibfly2(int x){ return dpp_i<0x4E>(x); }
__device__ __forceinline__ int ibfly1(int x){ return dpp_i<0xB1>(x); }

// bit-identical to original: inter / ((areaA + areaB) - inter)
__device__ __forceinline__ float iou4(float4 a, float4 b, float areaSum) {
    float xx1 = fmaxf(a.x, b.x);
    float yy1 = fmaxf(a.y, b.y);
    float xx2 = fminf(a.z, b.z);
    float yy2 = fminf(a.w, b.w);
    float w = fmaxf(0.f, xx2 - xx1 + 1.f);
    float h = fmaxf(0.f, yy2 - yy1 + 1.f);
    float inter = w * h;
    return inter / (areaSum - inter);
}

__global__ __launch_bounds__(NT, 4) void hoi_kernel(
    const float* __restrict__ obj_logits,   // B,Q,C
    const float* __restrict__ verb_logits,  // B,Q,V
    const float* __restrict__ sub_boxes_in, // B,Q,4
    const float* __restrict__ obj_boxes_in, // B,Q,4
    const float* __restrict__ cm,           // V,C
    const int*   __restrict__ tsizes,       // B,2 (h,w)
    float* __restrict__ out)
{
    const int b = blockIdx.x;
    const int tid = threadIdx.x;

    __shared__ __align__(16) u8 smem[SMEM_SZ];
    float* ldsLog  = (float*)(smem + 0);               // phases 0-4 (aliases cm region)
    float* cml     = (float*)(smem + OFF_CM);          // phase >= 5
    u32*   hist    = (u32*)(smem + OFF_HIST);
    u64*   cand    = (u64*)(smem + OFF_HIST);
    float* asub    = (float*)(smem + OFF_HIST);        // phase>=5.5 (hist/cand dead)
    float* aobj    = (float*)(smem + OFF_HIST + 512);  // phase>=5.5
    float* rowmax  = (float*)(smem + OFF_RMAX);
    float* rinv    = (float*)(smem + OFF_RINV);
    float (*bsub)[4]   = (float(*)[4])(smem + OFF_BSUB);
    float (*bobj)[4]   = (float(*)[4])(smem + OFF_BOBJ);
    u32   (*supcol)[4] = (u32(*)[4])(smem + OFF_SUPR); // column-major suppression bits
    float* sel_val = (float*)(smem + OFF_SELV);
    u32*   sel_idx = (u32*)(smem + OFF_SELI);
    u32*   maxbits = (u32*)(smem + OFF_MAXB);
    u8*    order8  = (u8*)(smem + OFF_ORD);
    u8*    lab8    = (u8*)(smem + OFF_LAB);
    u32*   skeep     = (u32*)(smem + OFF_MISC);
    u32*   keep_bits = (u32*)(smem + OFF_MISC + 16);
    u32*   s_cnt     = (u32*)(smem + OFF_MISC + 32);
    int*   sT        = (int*)(smem + OFF_MISC + 36);
    u64*   wred    = (u64*)(smem + OFF_BOBJ);   // 5c scratch
    u64*   s_prev  = (u64*)(smem + OFF_SUPR);   // 5c scratch

    const float* lg = obj_logits + (size_t)b * QC_;

    // ---- Output pointers (concatenated in return order) ----
    float* o0 = out;                                   // final_scores B,K,V
    float* o1 = out + (size_t)B_ * KV_;                // topk_values  B,K
    float* o2 = o1 + (size_t)B_ * K_;                  // obj_labels   B,K
    float* o3 = o2 + (size_t)B_ * K_;                  // sub_boxes    B,K,4
    float* o4 = o3 + (size_t)B_ * K_ * 4;              // obj_boxes    B,K,4
    float* o5 = o4 + (size_t)B_ * K_ * 4;              // keep         B,K

    // ---- Phase 0: async-stage logits rows 0..95 into LDS via
    // global_load_lds (NO destination VGPRs -> all loads in flight at once,
    // immune to the allocator's 32-VGPR budget that re-serialized r11/r12's
    // register-resident loads). Zero hist meanwhile; one vmcnt-drain
    // barrier publishes the staged data. Dest = wave-uniform base +
    // lane*16 (HW rule); src 16B-aligned (b*97200 % 16 == 0). ----
    {
        const float4* lgb4 = (const float4*)lg;
        const int w64 = tid >> 6;
        // issue 1: float4 f = tid (all 1024 threads)
        __builtin_amdgcn_global_load_lds(
            (const __attribute__((address_space(1))) void*)(lgb4 + tid),
            (__attribute__((address_space(3))) void*)(smem + w64 * 1024),
            16, 0, 0);
        // issue 2: f = 1024 + tid (tid < 920)
        if (tid < NF4 - NT) {
            __builtin_amdgcn_global_load_lds(
                (const __attribute__((address_space(1))) void*)(lgb4 + NT + tid),
                (__attribute__((address_space(3))) void*)(smem + 16384 + w64 * 1024),
                16, 0, 0);
        }
    }
    if (tid < NB * HREP) hist[tid] = 0;
    if (tid == 0) *s_cnt = 0;
    asm volatile("s_waitcnt vmcnt(0) lgkmcnt(0)\n\ts_barrier" ::: "memory");

    // ---- Phase 1 (fused): softmax + histogram. s=0..2 (rows 0..95) read
    // from staged LDS; s=3..9 direct from HBM (issued first so they drain
    // under the LDS reads + A-half compute). Two 5-row compute halves (r12)
    // keep liveness within the allocator's budget. Per-row arithmetic +
    // reduce pairing identical -> bit-identical.
    const int g = tid >> 5, l = tid & 31;
    const bool have2 = (l < C_ - 64);   // l < 17
    const int hsub = tid & (HREP - 1);
    u32 cmask = 0;
    {
        float A0[5], A1[5], A2[5], B0[5], B1[5], B2[5];
        #pragma unroll
        for (int s = 0; s < 5; ++s) {           // B half direct: s=5..9
            int r = g + 32 * (s + 5);
            const float* row = lg + (size_t)((r < Q_ ? r : Q_ - 1) * C_);
            B0[s] = row[l];
            B1[s] = row[l + 32];
            B2[s] = have2 ? row[l + 64] : -INFINITY;
        }
        #pragma unroll
        for (int s = 3; s < 5; ++s) {           // A tail direct: r=96..159 (<Q_)
            int r = g + 32 * s;
            const float* row = lg + (size_t)(r * C_);
            A0[s] = row[l];
            A1[s] = row[l + 32];
            A2[s] = have2 ? row[l + 64] : -INFINITY;
        }
        #pragma unroll
        for (int s = 0; s < 3; ++s) {           // A head from staged LDS
            int base = (g + 32 * s) * C_;
            A0[s] = ldsLog[base + l];
            A1[s] = ldsLog[base + l + 32];
            A2[s] = have2 ? ldsLog[base + l + 64] : -INFINITY;
        }

        auto half5 = [&](float* v0, float* v1, float* v2, int sb) {
            float m[5];
            #pragma unroll
            for (int s = 0; s < 5; ++s) m[s] = fmaxf(fmaxf(v0[s], v1[s]), v2[s]);
            #pragma unroll
            for (int s = 0; s < 5; ++s) m[s] = fmaxf(m[s], bfly16(m[s]));
            #pragma unroll
            for (int s = 0; s < 5; ++s) m[s] = fmaxf(m[s], bfly8(m[s]));
            #pragma unroll
            for (int s = 0; s < 5; ++s) m[s] = fmaxf(m[s], bfly4(m[s]));
            #pragma unroll
            for (int s = 0; s < 5; ++s) m[s] = fmaxf(m[s], bfly2(m[s]));
            #pragma unroll
            for (int s = 0; s < 5; ++s) m[s] = fmaxf(m[s], bfly1(m[s]));
            float e0[5], e1[5], e2[5], sm[5];
            #pragma unroll
            for (int s = 0; s < 5; ++s) {
                e0[s] = expf(v0[s] - m[s]);
                e1[s] = expf(v1[s] - m[s]);
                e2[s] = have2 ? expf(v2[s] - m[s]) : 0.f;
                sm[s] = e0[s] + e1[s] + e2[s];
            }
            #pragma unroll
            for (int s = 0; s < 5; ++s) sm[s] += bfly16(sm[s]);
            #pragma unroll
            for (int s = 0; s < 5; ++s) sm[s] += bfly8(sm[s]);
            #pragma unroll
            for (int s = 0; s < 5; ++s) sm[s] += bfly4(sm[s]);
            #pragma unroll
            for (int s = 0; s < 5; ++s) sm[s] += bfly2(sm[s]);
            #pragma unroll
            for (int s = 0; s < 5; ++s) sm[s] += bfly1(sm[s]);
            #pragma unroll
            for (int s = 0; s < 5; ++s) {
                int sg = sb + s;
                int r = g + 32 * sg;
                if (r < Q_) {
                    float ri = 1.f / sm[s];
                    float p0 = e0[s] * ri, p1 = e1[s] * ri;
                    u32 x0 = __float_as_uint(p0), x1 = __float_as_uint(p1);
                    if (x0 >= PCUT_BITS) {
                        atomicAdd(&hist[(((x0 >> 21) - BIN0) << 3) + hsub], 1u);
                        cmask |= 1u << (3 * sg);
                    }
                    if (x1 >= PCUT_BITS) {
                        atomicAdd(&hist[(((x1 >> 21) - BIN0) << 3) + hsub], 1u);
                        cmask |= 1u << (3 * sg + 1);
                    }
                    if (have2) {
                        float p2 = e2[s] * ri;
                        u32 x2 = __float_as_uint(p2);
                        if (x2 >= PCUT_BITS) {
                            atomicAdd(&hist[(((x2 >> 21) - BIN0) << 3) + hsub], 1u);
                            cmask |= 1u << (3 * sg + 2);
                        }
                    }
                    if (l == 0) { rowmax[RM(r)] = m[s]; rinv[RM(r)] = ri; }
                }
            }
        };
        half5(A0, A1, A2, 0);   // B's 15 loads keep draining underneath
        half5(B0, B1, B2, 5);
    }
    bar_lds();

    // ---- Phase 3: threshold bin T — sum 8 sub-counters, 64-bin suffix scan ----
    if (tid < 64) {
        uint4 ha = ((const uint4*)hist)[tid * 2];
        uint4 hb = ((const uint4*)hist)[tid * 2 + 1];
        u32 suf = ha.x + ha.y + ha.z + ha.w + hb.x + hb.y + hb.z + hb.w;
        #pragma unroll
        for (int off = 1; off < 64; off <<= 1) {
            u32 o = (u32)__shfl_down((int)suf, off, 64);
            suf += (tid + off < 64) ? o : 0;
        }
        u32 nxt = (u32)__shfl_down((int)suf, 1, 64);
        if (tid == 63) nxt = 0;
        if (suf >= (u32)K_ && nxt < (u32)K_) *sT = BIN0 + tid;
    }
    bar_lds();   // T visible; hist dead (cand may alias)
    const int T = *sT;

    // ---- Phase 4: candidate scan driven by the mask — recompute prob,
    // bit-identical to phase 1 (same expf(v-m)*ri, same m/ri from LDS;
    // staged rows read the identical bits from ldsLog). ----
    u32 mk = cmask;
    while (mk) {
        int bpos = (int)__builtin_ctz(mk);
        mk &= mk - 1;
        int s = (bpos * 171) >> 9;       // floor(bpos/3) for bpos in [0,30)
        int c = bpos - 3 * s;
        int r = g + 32 * s;
        int col = l + 32 * c;
        int i = r * C_ + col;
        float lv = (i < NSTG * C_) ? ldsLog[i] : lg[i];
        float p = expf(lv - rowmax[RM(r)]) * rinv[RM(r)];
        u32 xb = __float_as_uint(p);
        if ((int)(xb >> 21) >= T) {
            u32 pos = atomicAdd(s_cnt, 1u);
            if (pos < (u32)CAP)
                cand[pos] = ((u64)xb << 32) | (u32)(~i);
        }
    }
    bar_lds();
    const int ncand = (int)*s_cnt;

    // ---- cm staging: issue 3 float4 loads/thread; rank scan runs under
    // their latency; ds_writes + bar_lds publish cml before phase 6.
    // (cml overwrites ldsLog — last ldsLog read was phase 4, above.) ----
    constexpr int CM4 = CMN / 4;              // 2369
    const float4* cmg4 = (const float4*)cm;
    float4 cc0 = cmg4[tid];
    float4 cc1 = cmg4[tid + NT];
    float4 cc2 = (tid < CM4 - 2 * NT) ? cmg4[tid + 2 * NT]
                                      : make_float4(0.f, 0.f, 0.f, 0.f);
    float ctail = (tid == 0) ? cm[CMN - 1] : 0.f;   // 9477 = 2369*4 + 1

    if (ncand <= CAP) {
        // ---- Phase 5: parallel rank-by-count top-K select (broadcast reads) ----
        if (tid < ncand) {
            u64 mykey = cand[tid];
            int rank = 0;
            int f = 0;
            for (; f + 4 <= ncand; f += 4) {
                u64 k0 = cand[f], k1 = cand[f + 1];
                u64 k2 = cand[f + 2], k3 = cand[f + 3];
                rank += (k0 > mykey) ? 1 : 0;
                rank += (k1 > mykey) ? 1 : 0;
                rank += (k2 > mykey) ? 1 : 0;
                rank += (k3 > mykey) ? 1 : 0;
            }
            for (; f < ncand; ++f) rank += (cand[f] > mykey) ? 1 : 0;
            if (rank < K_) {
                sel_val[rank] = __uint_as_float((u32)(mykey >> 32));
                sel_idx[rank] = ~(u32)mykey;
            }
        }
    } else {
        // ---- Phase 5c (near-dead): 100-round argmax with strict-less chaining ----
        if (tid == 0) *s_prev = ~0ull;
        __syncthreads();
        for (int r = 0; r < K_; r++) {
            u64 prev = *s_prev;
            u64 local = 0;
            for (int i = tid; i < QC_; i += NT) {
                int q = i / C_;
                float p = expf(lg[i] - rowmax[RM(q)]) * rinv[RM(q)];
                u64 key = ((u64)__float_as_uint(p) << 32) | (u32)(~i);
                if (key < prev && key > local) local = key;
            }
            for (int off = 32; off > 0; off >>= 1) {
                u64 o = shfl_xor_u64(local, off);
                if (o > local) local = o;
            }
            if ((tid & 63) == 0) wred[tid >> 6] = local;
            __syncthreads();
            if (tid == 0) {
                u64 m = wred[0];
                for (int wv = 1; wv < 16; wv++) if (wred[wv] > m) m = wred[wv];
                *s_prev = m;
                u32 idx = ~(u32)m;
                if (idx >= (u32)QC_) idx = 0;
                sel_val[r] = __uint_as_float((u32)(m >> 32));
                sel_idx[r] = idx;
            }
            __syncthreads();
        }
    }

    // publish cm to LDS (loads have had the whole rank scan to complete)
    ((float4*)cml)[tid] = cc0;
    ((float4*)cml)[tid + NT] = cc1;
    if (tid < CM4 - 2 * NT) ((float4*)cml)[tid + 2 * NT] = cc2;
    if (tid == 0) cml[CMN - 1] = ctail;
    bar_lds();   // sel_* AND cml visible; hist/cand/rowstats/ldsLog dead

    // ---- Fused phase 5.5+6+6.5 (full-wave per-row, r11). ----
    const int w = tid >> 6, lane = tid & 63;
    const int off0 = lane * C_;             // cml col offsets, lane-invariant
    const int off1 = (lane + 64) * C_;
    const bool l53 = (lane < V_ - 64);      // lane < 53

    const bool doSub = (tid < K_);
    const bool doObj = (tid >= 512 && tid < 512 + K_);
    float4 boxv = make_float4(0.f, 0.f, 0.f, 0.f);
    float biw = 0.f, bih = 0.f;
    if (doSub || doObj) {
        int t = doSub ? tid : tid - 512;
        int idx = (int)sel_idx[t];
        int q = idx / C_;
        biw = (float)tsizes[b * 2 + 1];
        bih = (float)tsizes[b * 2 + 0];
        boxv = doSub ? ((const float4*)sub_boxes_in)[(size_t)b * Q_ + q]
                     : ((const float4*)obj_boxes_in)[(size_t)b * Q_ + q];
    }
    if (tid >= 200 && tid < 200 + K_) {
        int t = tid - 200;
        supcol[t][0] = 0; supcol[t][1] = 0; supcol[t][2] = 0; supcol[t][3] = 0;
    } else if (tid >= 320 && tid < 324) {
        keep_bits[tid - 320] = 0;
    }

    {
        const float* vbase = verb_logits + (size_t)b * Q_ * V_;
        float* obase = o0 + (size_t)b * KV_;
        int c = w;                                   // w < 16 <= 100: >=1 row/wave
        u32 idx = sel_idx[c];
        int q = (int)idx / C_, lab = (int)idx - q * C_;
        float sv = sel_val[c];
        const float* vr = vbase + (size_t)q * V_;
        float x0 = vr[lane];
        float x1 = l53 ? vr[lane + 64] : 0.f;
        while (true) {
            int cn = c + 16;                         // wave-uniform
            int labn = 0; float svn = 0.f, x0n = 0.f, x1n = 0.f;
            if (cn < K_) {                           // prefetch next row
                u32 idxn = sel_idx[cn];
                int qn = (int)idxn / C_;
                labn = (int)idxn - qn * C_;
                svn = sel_val[cn];
                const float* vrn = vbase + (size_t)qn * V_;
                x0n = vrn[lane];
                x1n = l53 ? vrn[lane + 64] : 0.f;
            }
            // compute current row (expression order identical to before)
            float cv0 = cml[off0 + lab];
            float cv1 = l53 ? cml[off1 + lab] : 0.f;
            float h0 = (1.f / (1.f + expf(-x0))) * sv * cv0;
            float h1 = l53 ? (1.f / (1.f + expf(-x1))) * sv * cv1 : 0.f;
            float* orow = obase + c * V_;
            orow[lane] = h0;
            if (l53) orow[lane + 64] = h1;
            float m = fmaxf(h0, h1);                 // h >= 0; fmax exact
            m = fmaxf(m, __shfl_xor(m, 32, 64));
            m = fmaxf(m, bfly16(m));
            m = fmaxf(m, bfly8(m));
            m = fmaxf(m, bfly4(m));
            m = fmaxf(m, bfly2(m));
            m = fmaxf(m, bfly1(m));
            if (lane == 0) { maxbits[c] = __float_as_uint(m); lab8[c] = (u8)lab; }
            if (cn >= K_) break;
            c = cn; lab = labn; sv = svn; x0 = x0n; x1 = x1n;
        }
    }

    // finish boxes (loads issued before the row loop)
    if (doSub) {
        int t = tid;
        float x1v = (boxv.x - 0.5f * boxv.z) * biw, y1v = (boxv.y - 0.5f * boxv.w) * bih;
        float x2v = (boxv.x + 0.5f * boxv.z) * biw, y2v = (boxv.y + 0.5f * boxv.w) * bih;
        bsub[t][0] = x1v; bsub[t][1] = y1v; bsub[t][2] = x2v; bsub[t][3] = y2v;
        asub[t] = (x2v - x1v + 1.f) * (y2v - y1v + 1.f);
    } else if (doObj) {
        int t = tid - 512;
        float x1v = (boxv.x - 0.5f * boxv.z) * biw, y1v = (boxv.y - 0.5f * boxv.w) * bih;
        float x2v = (boxv.x + 0.5f * boxv.z) * biw, y2v = (boxv.y + 0.5f * boxv.w) * bih;
        bobj[t][0] = x1v; bobj[t][1] = y1v; bobj[t][2] = x2v; bobj[t][3] = y2v;
        aobj[t] = (x2v - x1v + 1.f) * (y2v - y1v + 1.f);
    }
    bar_lds();   // LDS (maxbits/lab8/boxes/areas/supcol/keep_bits) visible;
                 // o0 global stores keep draining underneath phases 7/8

    // ---- Phase 7: stable descending rank, 8 lanes/row, exact int sums ----
    if (tid < 800) {
        int r = tid >> 3, j = tid & 7;
        u64 kr = ((u64)maxbits[r] << 32) | (u32)(~r);
        int rank = 0;
        for (int k = 0; k < 13; k++) {
            int jj = j * 13 + k;
            if (jj < K_) {
                u64 kj = ((u64)maxbits[jj] << 32) | (u32)(~jj);
                rank += (kj > kr) ? 1 : 0;
            }
        }
        rank += ibfly4(rank);
        rank += ibfly2(rank);
        rank += ibfly1(rank);
        if (j == 0) order8[rank] = (u8)r;
    }
    bar_lds();

    // ---- Early output writes: o1..o4 depend only on sel/boxes (NOT keep) ----
    if (tid < K_) {
        o1[(size_t)b * K_ + tid] = sel_val[tid];
        o2[(size_t)b * K_ + tid] = (float)(sel_idx[tid] % (u32)C_);
    }
    if (tid >= 128 && tid < 128 + K_ * 4) {
        int t = tid - 128;
        int r = t >> 2, k = t & 3;
        o3[((size_t)b * K_) * 4 + t] = bsub[r][k];
        o4[((size_t)b * K_) * 4 + t] = bobj[r][k];
    }

    // ---- Phase 8a: 100x100 suppression bitmatrix, COLUMN-major
    // (division-free index stepping: e += NT <=> i += 10, j += 24) ----
    {
        int i = tid / K_, j = tid - (tid / K_) * K_;
        for (int e = tid; e < K_ * K_; e += NT) {
            if (j > i) {
                int ri = order8[i], rj = order8[j];
                u32 li = lab8[ri], lj = lab8[rj];
                if (li == lj) {
                    float4 s_i = *(const float4*)bsub[ri];
                    float4 s_j = *(const float4*)bsub[rj];
                    float4 b_i = *(const float4*)bobj[ri];
                    float4 b_j = *(const float4*)bobj[rj];
                    float o = iou4(s_i, s_j, asub[ri] + asub[rj]) *
                              iou4(b_i, b_j, aobj[ri] + aobj[rj]);
                    if (o > 0.5f)
                        atomicOr(&supcol[j][i >> 5], 1u << (i & 31));
                }
            }
            i += 10; j += 24;                  // NT = 10*K_ + 24
            if (j >= K_) { j -= K_; i += 1; }
        }
    }
    bar_lds();

    // ---- Phase 8b: greedy scan via ballot ----
    if (tid < 64) {
        u32 cA[4], cB[4];
        #pragma unroll
        for (int ww = 0; ww < 4; ++ww) cA[ww] = supcol[tid][ww];
        #pragma unroll
        for (int ww = 0; ww < 4; ++ww) cB[ww] = (tid < K_ - 64) ? supcol[tid + 64][ww] : 0u;
        bool sA = false, sB = false;
        u32 km[4] = {0, 0, 0, 0};
        #pragma unroll
        for (int i = 0; i < 64; ++i) {
            u64 bal = __ballot(sA);
            if (!((bal >> i) & 1)) {          // uniform branch
                km[i >> 5] |= 1u << (i & 31);
                sA = sA || ((cA[i >> 5] >> (i & 31)) & 1u);
                sB = sB || ((cB[i >> 5] >> (i & 31)) & 1u);
            }
        }
        #pragma unroll
        for (int i = 64; i < K_; ++i) {
            u64 bal = __ballot(sB);
            if (!((bal >> (i - 64)) & 1)) {   // uniform branch
                km[i >> 5] |= 1u << (i & 31);
                sA = sA || ((cA[i >> 5] >> (i & 31)) & 1u);
                sB = sB || ((cB[i >> 5] >> (i & 31)) & 1u);
            }
        }
        if (tid == 0) { skeep[0] = km[0]; skeep[1] = km[1]; skeep[2] = km[2]; skeep[3] = km[3]; }
    }
    bar_lds();
    if (tid < K_) {
        if ((skeep[tid >> 5] >> (tid & 31)) & 1u) {
            int r = order8[tid];
            atomicOr(&keep_bits[r >> 5], 1u << (r & 31));
        }
    }
    // FULL barrier (vmcnt drain): guarantees every wave's phase-6 o0 stores
    // are complete before phase 9's zeroing stores to the same addresses.
    __syncthreads();

    // ---- Phase 9: zero suppressed rows of o0 (per-wave coalesced), o5 keep ----
    for (int c = w; c < K_; c += 16) {
        if (!((keep_bits[c >> 5] >> (c & 31)) & 1u)) {
            float* orow = o0 + (size_t)b * KV_ + c * V_;
            orow[lane] = 0.f;
            if (l53) orow[lane + 64] = 0.f;
        }
    }
    if (tid < K_) {
        bool kp = (keep_bits[tid >> 5] >> (tid & 31)) & 1u;
        o5[(size_t)b * K_ + tid] = kp ? 1.f : 0.f;
    }
}

extern "C" void kernel_launch(void* const* d_in, const int* in_sizes, int n_in,
                              void* d_out, int out_size, void* d_ws, size_t ws_size,
                              hipStream_t stream) {
    const float* obj_logits  = (const float*)d_in[0];
    const float* verb_logits = (const float*)d_in[1];
    const float* sub_boxes   = (const float*)d_in[2];
    const float* obj_boxes   = (const float*)d_in[3];
    const float* cm          = (const float*)d_in[4];
    const int*   ts          = (const int*)d_in[5];
    hipLaunchKernelGGL(hoi_kernel, dim3(B_), dim3(NT), 0, stream,
                       obj_logits, verb_logits, sub_boxes, obj_boxes, cm, ts,
                       (float*)d_out);
}